// Round 8
// baseline (123.383 us; speedup 1.0000x reference)
//
#include <hip/hip_runtime.h>
#include <hip/hip_bf16.h>

// Shapes are fixed by the problem definition.
#define B_   16
#define T_   4096
#define N_   512
#define D_   512
#define EPSF 1e-8f

typedef __attribute__((ext_vector_type(8))) short bf16x8; // 8 bf16 = 4 VGPRs
typedef __attribute__((ext_vector_type(4))) float f32x4;

// round-to-nearest-even f32 -> bf16, packed pair into one u32
__device__ __forceinline__ unsigned int pack2bf(float a, float b) {
  unsigned int ua = __float_as_uint(a);
  ua += 0x7fffu + ((ua >> 16) & 1u);
  unsigned int ub = __float_as_uint(b);
  ub += 0x7fffu + ((ub >> 16) & 1u);
  return (ua >> 16) | (ub & 0xffff0000u);
}

// async global->LDS, 16 B per lane
__device__ __forceinline__ void gload_lds16(const void* g, void* l) {
  __builtin_amdgcn_global_load_lds(
      (const __attribute__((address_space(1))) unsigned int*)g,
      (__attribute__((address_space(3))) unsigned int*)l, 16, 0, 0);
}

// ---------------------------------------------------------------------------
// Kernel A: distractor rows -> inv_nd (f32 norms) + bf16 copy (ydbf).
// ---------------------------------------------------------------------------
__global__ void rownorms_d(const float* __restrict__ yd,
                           float* __restrict__ inv_nd,
                           unsigned short* __restrict__ ydbf) {
  const int tid = threadIdx.x;
  const int g   = tid >> 4;
  const int t   = tid & 15;
  const int row = blockIdx.x * 16 + g;
  const float* dr = yd + (size_t)row * D_;
  unsigned short* ob = ydbf + (size_t)row * D_;

  float dd = 0.f;
#pragma unroll
  for (int k = 0; k < 8; ++k) {
    const int col = k * 64 + t * 4;
    float4 a = *(const float4*)(dr + col);
    dd += a.x * a.x + a.y * a.y + a.z * a.z + a.w * a.w;
    uint2 p;
    p.x = pack2bf(a.x, a.y);
    p.y = pack2bf(a.z, a.w);
    *(uint2*)(ob + col) = p;
  }
#pragma unroll
  for (int m = 1; m < 16; m <<= 1) dd += __shfl_xor(dd, m);
  if (t == 0) inv_nd[row] = 1.f / fmaxf(sqrtf(dd), EPSF);
}

// ---------------------------------------------------------------------------
// Kernel B (r8): one block per (mt,b) = 32-row band x full N=512.
// 256 threads / 4 waves; wave w owns cols w*128 (acc[2][8] = 64 regs).
// LDS: Bs 64 KB + As 4 KB + stats 2.2 KB = 70.2 KB -> 2 independent
// resident blocks/CU (two barrier domains per CU -> staggered phases keep
// HBM demand continuous; r4-r7's single 8-wave domain streamed at only
// 1.3-2.0 TB/s because each iter drained vmcnt to zero then computed).
// Stats (inv_nc, rt) fold into A staging: c & yt read exactly once.
// All LDS addressing formulas verbatim from r6 (verified, 0 conflicts).
// ---------------------------------------------------------------------------
__launch_bounds__(256, 2)
__global__ void fused_ct(const float* __restrict__ c,
                         const float* __restrict__ yt,
                         const unsigned short* __restrict__ ydbf,
                         const float* __restrict__ inv_nd,
                         float* __restrict__ rt,
                         float* __restrict__ S) {
  __shared__ __align__(16) unsigned char Bs[512 * 64 * 2];  // 64 KB
  __shared__ __align__(16) unsigned char As[32 * 64 * 2];   // 4 KB
  __shared__ float s_invc[32];
  __shared__ float s_invd[512];

  const int mt = blockIdx.x;            // 0..127 (32-row bands)
  const int b  = blockIdx.y;
  const int tid  = threadIdx.x;
  const int lane = tid & 63;
  const int w    = tid >> 6;            // wave 0..3 -> cols w*128

  const float* Ab = c  + ((size_t)b * T_ + (size_t)mt * 32) * D_;
  const float* Tb = yt + ((size_t)b * T_ + (size_t)mt * 32) * D_;
  const unsigned short* Bb = ydbf + (size_t)b * N_ * D_;

  float4 va[2], vb[2];
  float cc[2] = {0.f, 0.f}, tt[2] = {0.f, 0.f}, ct[2] = {0.f, 0.f};

  // ---- helpers inlined as lambdas (static indexing throughout) ----
  auto loadA = [&](int k0) {
#pragma unroll
    for (int j = 0; j < 2; ++j) {
      const int g   = j * 256 + tid;      // float4 idx 0..511 (32 rows x 16)
      const int row = g >> 4;
      const int c4  = g & 15;
      const size_t off = (size_t)row * D_ + k0 + (c4 << 2);
      va[j] = *(const float4*)(Ab + off);
      vb[j] = *(const float4*)(Tb + off);
    }
  };
  auto writeA = [&]() {
#pragma unroll
    for (int j = 0; j < 2; ++j) {
      const int g   = j * 256 + tid;
      const int row = g >> 4;
      const int c4  = g & 15;
      const int off = (row << 7) + ((((c4 >> 1) ^ (row & 7))) << 4) + ((c4 & 1) << 3);
      uint2 pa;
      pa.x = pack2bf(va[j].x, va[j].y);
      pa.y = pack2bf(va[j].z, va[j].w);
      *(uint2*)(As + off) = pa;
      cc[j] += va[j].x * va[j].x + va[j].y * va[j].y + va[j].z * va[j].z + va[j].w * va[j].w;
      tt[j] += vb[j].x * vb[j].x + vb[j].y * vb[j].y + vb[j].z * vb[j].z + vb[j].w * vb[j].w;
      ct[j] += va[j].x * vb[j].x + va[j].y * vb[j].y + va[j].z * vb[j].z + va[j].w * vb[j].w;
    }
  };
  auto stageB = [&](int k0) {
#pragma unroll
    for (int j = 0; j < 16; ++j) {
      const int g   = j * 256 + tid;      // chunk 0..4095 (16 B each)
      const int row = g >> 3;             // 8 chunks per 64-bf16 row
      const int sch = (g & 7) ^ (row & 7);
      gload_lds16(Bb + (size_t)row * D_ + k0 + (sch << 3), Bs + (g << 4));
    }
  };

  // ---- prologue: tile 0 ----
  loadA(0);
  stageB(0);
  s_invd[tid] = inv_nd[b * N_ + tid];
  s_invd[tid + 256] = inv_nd[b * N_ + tid + 256];
  writeA();
  __syncthreads();   // As(0) visible; Bs(0) gloads drained

  f32x4 acc[2][8] = {};

  // ---- K-loop: 8 iters of BK=64, single-buffered (partner block covers) ----
  for (int t = 0; t < 8; ++t) {
    if (t < 7) loadA((t + 1) * 64);   // early issue; drained at barrier1

#pragma unroll
    for (int ks = 0; ks < 2; ++ks) {
      const int kc = ks * 4 + (lane >> 4);
      bf16x8 af[2], bfr[8];
#pragma unroll
      for (int i = 0; i < 2; ++i) {
        const int ar = i * 16 + (lane & 15);      // rows 0..31
        af[i] = *(const bf16x8*)(As + (ar << 7) + ((kc ^ (ar & 7)) << 4));
      }
#pragma unroll
      for (int n = 0; n < 8; ++n) {
        const int br = w * 128 + n * 16 + (lane & 15);
        bfr[n] = *(const bf16x8*)(Bs + (br << 7) + ((kc ^ (br & 7)) << 4));
      }
#pragma unroll
      for (int mi = 0; mi < 2; ++mi)
#pragma unroll
        for (int ni = 0; ni < 8; ++ni)
          acc[mi][ni] = __builtin_amdgcn_mfma_f32_16x16x32_bf16(
              af[mi], bfr[ni], acc[mi][ni], 0, 0, 0);
    }

    __syncthreads();                   // everyone done reading As/Bs
    if (t < 7) {
      stageB((t + 1) * 64);            // overwrite Bs (safe now)
      writeA();                        // cvt + ds_write + stats
      __syncthreads();                 // drain gloads + ds_writes
    }
  }

  // ---- stats reduction: rows j*16 + (tid>>4), 16-lane groups ----
#pragma unroll
  for (int j = 0; j < 2; ++j) {
#pragma unroll
    for (int m = 1; m < 16; m <<= 1) {
      cc[j] += __shfl_xor(cc[j], m);
      tt[j] += __shfl_xor(tt[j], m);
      ct[j] += __shfl_xor(ct[j], m);
    }
    if ((tid & 15) == 0) {
      const int row = j * 16 + (tid >> 4);
      const float nc = fmaxf(sqrtf(cc[j]), EPSF);
      const float nt = fmaxf(sqrtf(tt[j]), EPSF);
      s_invc[row] = 1.f / nc;
      rt[b * T_ + mt * 32 + row] = ct[j] / (nt * nc);
    }
  }
  __syncthreads();

  // ---- epilogue: exp(acc*invc*invd) row-sum, atomicAdd into S ----
  float invd[8];
#pragma unroll
  for (int ni = 0; ni < 8; ++ni)
    invd[ni] = s_invd[w * 128 + ni * 16 + (lane & 15)];

#pragma unroll
  for (int mi = 0; mi < 2; ++mi) {
    const int t0l = mi * 16 + ((lane >> 4) << 2);   // local row
#pragma unroll
    for (int r = 0; r < 4; ++r) {
      const float invc = s_invc[t0l + r];
      float s = 0.f;
#pragma unroll
      for (int ni = 0; ni < 8; ++ni)
        s += __expf(acc[mi][ni][r] * invc * invd[ni]);
      s += __shfl_xor(s, 1);
      s += __shfl_xor(s, 2);
      s += __shfl_xor(s, 4);
      s += __shfl_xor(s, 8);
      if ((lane & 15) == 0)
        atomicAdd(&S[b * T_ + mt * 32 + t0l + r], s);
    }
  }
}

// ---------------------------------------------------------------------------
// Kernel C: loss = sum_{b,t} log(S + exp(r_t)) - r_t
// ---------------------------------------------------------------------------
__global__ void final_loss(const float* __restrict__ S,
                           const float* __restrict__ rt,
                           float* __restrict__ out) {
  const int tid = threadIdx.x;
  float sum = 0.f;
  for (int i = blockIdx.x * blockDim.x + tid; i < B_ * T_;
       i += gridDim.x * blockDim.x) {
    const float r = rt[i];
    sum += logf(S[i] + __expf(r)) - r;
  }
#pragma unroll
  for (int m = 32; m; m >>= 1) sum += __shfl_xor(sum, m);
  __shared__ float ws[4];
  if ((tid & 63) == 0) ws[tid >> 6] = sum;
  __syncthreads();
  if (tid == 0) atomicAdd(out, ws[0] + ws[1] + ws[2] + ws[3]);
}

// ---------------------------------------------------------------------------
extern "C" void kernel_launch(void* const* d_in, const int* in_sizes, int n_in,
                              void* d_out, int out_size, void* d_ws, size_t ws_size,
                              hipStream_t stream) {
  (void)in_sizes; (void)n_in; (void)out_size; (void)ws_size;
  const float* c  = (const float*)d_in[0];
  const float* yt = (const float*)d_in[1];
  const float* yd = (const float*)d_in[2];
  float* out = (float*)d_out;

  // ws layout: [ydbf: B*N*D u16][rt: B*T f][inv_nd: B*N f][S: B*T f]
  const size_t ydbf_n = (size_t)B_ * N_ * D_;   // 4.2M u16 = 8 MiB
  unsigned short* ydbf = (unsigned short*)d_ws;
  float* rt     = (float*)(ydbf + ydbf_n);      // B*T
  float* inv_nd = rt + B_ * T_;                 // B*N
  float* S      = inv_nd + B_ * N_;             // B*T

  hipMemsetAsync(S, 0, (size_t)B_ * T_ * sizeof(float), stream);
  hipMemsetAsync(out, 0, sizeof(float), stream);

  rownorms_d<<<B_ * N_ / 16, 256, 0, stream>>>(yd, inv_nd, ydbf);

  dim3 gF(T_ / 32, B_);   // (128, 16) = 2048 blocks, 256 threads
  fused_ct<<<gF, 256, 0, stream>>>(c, yt, ydbf, inv_nd, rt, S);

  final_loss<<<64, 256, 0, stream>>>(S, rt, out);
}